// Round 4
// baseline (24829.910 us; speedup 1.0000x reference)
//
#include <hip/hip_runtime.h>
#include <stdint.h>
#include <math.h>

// plmDCA one Gibbs sweep — bitwise-faithful replay of the JAX reference.
// Confirmed (r1, absmax 0.0): partitionable threefry (o0^o1), Eigen KC=288
// k-blocked left-fold sum order, f64-computed f32-rounded logs.
// r2 lesson: desynced blocks thrash L2/L3 (FETCH 0.54->10.9 GB). Keep 256
// blocks / 1 per CU, lockstep on the same J row.
// r3 lesson: VALU cut 2.4x, duration flat -> floor is the scattered GLOBAL
// gather (~21 cyc per wave-gather-instr, TA line serialization).
//
// r4: stream the J row chunk-wise into WAVE-PRIVATE LDS buffers (coalesced
// float4 loads, issue-early/write-late, double-buffered, no extra barriers),
// gather from LDS instead of global. Add order preserved exactly.

#define NSEQ 8192
#define LRES 256
#define QST  21
#define SPB  32                // sequences per block
#define NTHREADS (SPB * QST)   // 672
#define NWAVES 11              // ceil(672/64); wave 10 has 32 active lanes
#define CH   32                // l-chunk size
#define NCH  (LRES / CH)       // 8 chunks per step
#define SEGB 2688              // CH*21*4 bytes per a-segment
#define SEGPAD 64              // shifts 2nd segment's bank window by 16
#define BUFB (2 * SEGB + SEGPAD)   // 5440 B per buffer
#define WAVEB (2 * BUFB)           // 10880 B per wave (double buffer)

// Per-l KC-crossing table: 255 = plain add; else threshold on b for boundary m.
struct KcTbl {
  unsigned char thr[LRES];
  constexpr KcTbl() : thr() {
    for (int i = 0; i < LRES; ++i) thr[i] = 255;
    for (int m = 1; m < 19; ++m) {
      int l = (288 * m) / 21;
      thr[l] = (unsigned char)(288 * m - 21 * l);
    }
  }
};
static constexpr KcTbl KC_TBL{};

__device__ __forceinline__ uint32_t rotl32(uint32_t v, uint32_t r) {
  return (v << r) | (v >> (32u - r));
}

// JAX/Random123 Threefry-2x32, 20 rounds.
__device__ __forceinline__ void threefry2x32(uint32_t k0, uint32_t k1,
                                             uint32_t c0, uint32_t c1,
                                             uint32_t& o0, uint32_t& o1) {
  uint32_t ks2 = k0 ^ k1 ^ 0x1BD11BDAu;
  uint32_t x0 = c0 + k0;
  uint32_t x1 = c1 + k1;
#define TF_ROUND(r) { x0 += x1; x1 = rotl32(x1, r); x1 ^= x0; }
  TF_ROUND(13u) TF_ROUND(15u) TF_ROUND(26u) TF_ROUND(6u)
  x0 += k1;  x1 += ks2 + 1u;
  TF_ROUND(17u) TF_ROUND(29u) TF_ROUND(16u) TF_ROUND(24u)
  x0 += ks2; x1 += k0 + 2u;
  TF_ROUND(13u) TF_ROUND(15u) TF_ROUND(26u) TF_ROUND(6u)
  x0 += k0;  x1 += k1 + 3u;
  TF_ROUND(17u) TF_ROUND(29u) TF_ROUND(16u) TF_ROUND(24u)
  x0 += k1;  x1 += ks2 + 4u;
  TF_ROUND(13u) TF_ROUND(15u) TF_ROUND(26u) TF_ROUND(6u)
  x0 += ks2; x1 += k0 + 5u;
#undef TF_ROUND
  o0 = x0; o1 = x1;
}

// JAX gumbel: -log(-log(uniform(tiny,1))), logs f64-computed f32-rounded.
__device__ __forceinline__ float gumbel_f32(uint32_t bits) {
  float f = __uint_as_float((bits >> 9) | 0x3f800000u) - 1.0f;
  float u = fmaxf(1.17549435e-38f, f + 1.17549435e-38f);
  float w = (float)log((double)u);
  float t = -w;
  float g = -(float)log((double)t);
  return g;
}

__global__ __launch_bounds__(NTHREADS, 1)
void gibbs_sweep(const float* __restrict__ X, const int* __restrict__ order,
                 const float* __restrict__ h, const float* __restrict__ J,
                 const float* __restrict__ betaPtr, float* __restrict__ out) {
  __shared__ __align__(16) char jbuf[NWAVES * WAVEB];  // 119680 B wave-private stage
  __shared__ uint32_t sbst[(LRES / 4) * SPB];          // packed states (8 KB)
  __shared__ float    vals[QST][SPB];
  __shared__ uint32_t tk0[LRES], tk1[LRES];            // per-step threefry keys
  __shared__ int      sord[LRES];

  const int nl   = threadIdx.x;      // 0..31 local sequence
  const int a    = threadIdx.y;      // 0..20 category
  const int tid  = nl + SPB * a;     // 0..671
  const int lane = tid & 63;
  const int wv   = tid >> 6;         // wave id 0..10
  const int n0   = blockIdx.x * SPB;
  const int n    = n0 + nl;
  const float beta = betaPtr[0];

  // ---- init: keys, order cache ----
  for (int t = tid; t < LRES; t += NTHREADS) {
    uint32_t o0, o1;
    threefry2x32(0u, 42u, 0u, (uint32_t)t, o0, o1);
    tk0[t] = o0; tk1[t] = o1;
    sord[t] = order[t];
  }

  // ---- init packed state from one-hot X ----
  for (int idx = tid; idx < (LRES / 4) * SPB; idx += NTHREADS) {
    int s  = idx & (SPB - 1);
    int wg = idx / SPB;
    uint32_t w = 0;
#pragma unroll
    for (int j = 0; j < 4; ++j) {
      int l = 4 * wg + j;
      const float* xp = X + ((size_t)(n0 + s) * LRES + l) * QST;
      int b = 0;
#pragma unroll
      for (int q = 0; q < QST; ++q) b = (xp[q] > 0.5f) ? q : b;
      w |= ((uint32_t)b) << (8 * j);
    }
    sbst[wg * SPB + s] = w;
  }
  __syncthreads();

  // ---- staging helpers (wave-private; no barriers needed) ----
  const float4* Jv = (const float4*)J;           // J is 16B-aligned (harness alloc)
  const int  nact   = (wv == NWAVES - 1) ? 32 : 64;   // active lanes in this wave
  const int  nunits = (wv == NWAVES - 1) ? 168 : 336; // float4 units per chunk-stage
  char* wbase = jbuf + wv * WAVEB;

  // issue: global float4 loads for (row, chunk c) into regs (early)
  auto issue = [&](int row, int c, float4* r) {
    size_t rb = (size_t)row * 28224;             // row base in float4 units
#pragma unroll
    for (int k = 0; k < 6; ++k) {
      int u = lane + k * nact;
      if (u < nunits) {
        int s  = (u >= 168) ? 1 : 0;
        int w2 = u - (s ? 168 : 0);
        r[k] = Jv[rb + (size_t)((2 * wv + s) * 1344 + c * 168 + w2)];
      }
    }
  };
  // commit: regs -> LDS buffer bsel (late; compiler inserts vmcnt before use)
  auto commit = [&](int bsel, const float4* r) {
    float4* lv = (float4*)(wbase + bsel * BUFB);
#pragma unroll
    for (int k = 0; k < 6; ++k) {
      int u = lane + k * nact;
      if (u < nunits) {
        int s  = (u >= 168) ? 1 : 0;
        int w2 = u - (s ? 168 : 0);
        lv[s * 172 + w2] = r[k];                 // 172 = (SEGB+SEGPAD)/16
      }
    }
  };

  // prologue: stage chunk 0 of step 0 into buffer 0
  {
    float4 r[6];
    issue(sord[0], 0, r);
    commit(0, r);
  }

  // per-thread LDS gather bases for the two buffers
  const float* gbb0 = (const float*)(wbase + (a & 1) * (SEGB + SEGPAD));
  const float* gbb1 = (const float*)(wbase + BUFB + (a & 1) * (SEGB + SEGPAD));

  // ---- sequential Gibbs sweep ----
  for (int t = 0; t < LRES; ++t) {
    const int i     = sord[t];
    const int inext = sord[(t + 1) & (LRES - 1)];

    float tot = 0.0f, part = 0.0f;
#pragma unroll
    for (int c = 0; c < NCH; ++c) {
      float4 r[6];
      if (c < NCH - 1) issue(i, c + 1, r);       // overlap next chunk's loads
      else             issue(inext, 0, r);       // prefetch next step's chunk 0

      const float* gb = (c & 1) ? gbb1 : gbb0;
#pragma unroll
      for (int lg = 0; lg < CH / 4; ++lg) {
        uint32_t w = sbst[(c * (CH / 4) + lg) * SPB + nl];
#pragma unroll
        for (int j = 0; j < 4; ++j) {
          const int l = c * CH + 4 * lg + j;     // compile-time after unroll
          uint32_t b = (w >> (8 * j)) & 0xffu;
          float jv = gb[(4 * lg + j) * QST + b]; // LDS gather
          const int thr = KC_TBL.thr[l];         // folds at compile time
          if (thr == 255) {
            part += jv;
          } else if (thr == 0) {
            tot += part; part = jv;
          } else {
            if ((int)b >= thr) { tot += part; part = jv; }
            else               { part += jv; tot += part; part = 0.0f; }
          }
        }
      }
      commit((c + 1) & 1, r);                    // write-late into other buffer
    }
    tot += part;

    float lo = h[i * QST + a] + tot;

    uint32_t o0, o1;
    threefry2x32(tk0[t], tk1[t], 0u, (uint32_t)(n * QST + a), o0, o1);
    float g = gumbel_f32(o0 ^ o1);

    vals[a][nl] = g + beta * lo;
    __syncthreads();

    if (a == 0) {                                // first-max argmax over 21
      float best = vals[0][nl];
      int bi = 0;
#pragma unroll
      for (int q = 1; q < QST; ++q) {
        float vv = vals[q][nl];
        if (vv > best) { best = vv; bi = q; }
      }
      unsigned char* bp = reinterpret_cast<unsigned char*>(sbst);
      bp[((i >> 2) * SPB + nl) * 4 + (i & 3)] = (unsigned char)bi;
    }
    __syncthreads();
  }

  // ---- expand packed state to one-hot f32 output ----
  const size_t base = (size_t)n0 * LRES * QST;
  for (int idx = tid; idx < SPB * LRES * QST; idx += NTHREADS) {
    int s   = idx / (LRES * QST);
    int rem = idx - s * (LRES * QST);
    int l   = rem / QST;
    int q   = rem - l * QST;
    uint32_t w = sbst[(l >> 2) * SPB + s];
    int b = (int)((w >> (8 * (l & 3))) & 0xffu);
    out[base + idx] = (b == q) ? 1.0f : 0.0f;
  }
}

extern "C" void kernel_launch(void* const* d_in, const int* in_sizes, int n_in,
                              void* d_out, int out_size, void* d_ws, size_t ws_size,
                              hipStream_t stream) {
  const float* X     = (const float*)d_in[0];
  const int*   order = (const int*)  d_in[1];
  const float* h     = (const float*)d_in[2];
  const float* J     = (const float*)d_in[3];
  const float* beta  = (const float*)d_in[4];
  float* out = (float*)d_out;

  dim3 grid(NSEQ / SPB);      // 256 blocks, 1 per CU
  dim3 block(SPB, QST);       // 32 x 21 = 672 threads
  hipLaunchKernelGGL(gibbs_sweep, grid, block, 0, stream, X, order, h, J, beta, out);
}

// Round 5
// 11123.772 us; speedup vs baseline: 2.2321x; 2.2321x over previous
//
#include <hip/hip_runtime.h>
#include <stdint.h>
#include <math.h>

// plmDCA one Gibbs sweep — bitwise-faithful replay of the JAX reference.
// Confirmed (r1, absmax 0.0): partitionable threefry (o0^o1), Eigen KC=288
// k-blocked left-fold sum order, f64-computed f32-rounded logs.
// r2: desynced blocks thrash L2/L3 -> keep 256 blocks / 1 per CU, lockstep.
// r3: VALU cut 2.4x, duration flat -> floor is the scattered global gather.
// r4: reg-staged LDS pipeline SPILLED (WRITE_SIZE 45 GB, VALUBusy 5.8%) —
//     issue-early/write-late held 24 VGPRs across the gather phase.
// r5: same LDS-gather plan, but staging via global_load_lds (width=16, zero
//     VGPR), wave-private double buffer, counted vmcnt(6) (T4), raw
//     s_barrier + lgkmcnt only (no vmcnt drain across steps).

#define NSEQ 8192
#define LRES 256
#define QST  21
#define SPB  32                // sequences per block
#define NTHREADS (SPB * QST)   // 672
#define NWAVES 11              // wave 10 has 32 active lanes (a=20)
#define CH   32                // l-chunk size
#define NCH  (LRES / CH)       // 8 chunks per step
#define SEGB   2688            // CH*21*4 bytes per a-segment
#define SEGPAD 64              // shifts 2nd segment's bank window by 16
#define BUFB (2 * SEGB + SEGPAD)   // 5440 B per buffer
#define WAVEB (2 * BUFB)           // 10880 B per wave (double buffer)
#define ROWU 28224             // float4 units per J row (21*256*21/4)
#define SEGU 1344              // float4 units per a-strip
#define CHU  168               // float4 units per (a-strip, chunk)

// Per-l KC-crossing table: 255 = plain add; else threshold on b for boundary m.
struct KcTbl {
  unsigned char thr[LRES];
  constexpr KcTbl() : thr() {
    for (int i = 0; i < LRES; ++i) thr[i] = 255;
    for (int m = 1; m < 19; ++m) {
      int l = (288 * m) / 21;
      thr[l] = (unsigned char)(288 * m - 21 * l);
    }
  }
};
static constexpr KcTbl KC_TBL{};

__device__ __forceinline__ uint32_t rotl32(uint32_t v, uint32_t r) {
  return (v << r) | (v >> (32u - r));
}

// JAX/Random123 Threefry-2x32, 20 rounds.
__device__ __forceinline__ void threefry2x32(uint32_t k0, uint32_t k1,
                                             uint32_t c0, uint32_t c1,
                                             uint32_t& o0, uint32_t& o1) {
  uint32_t ks2 = k0 ^ k1 ^ 0x1BD11BDAu;
  uint32_t x0 = c0 + k0;
  uint32_t x1 = c1 + k1;
#define TF_ROUND(r) { x0 += x1; x1 = rotl32(x1, r); x1 ^= x0; }
  TF_ROUND(13u) TF_ROUND(15u) TF_ROUND(26u) TF_ROUND(6u)
  x0 += k1;  x1 += ks2 + 1u;
  TF_ROUND(17u) TF_ROUND(29u) TF_ROUND(16u) TF_ROUND(24u)
  x0 += ks2; x1 += k0 + 2u;
  TF_ROUND(13u) TF_ROUND(15u) TF_ROUND(26u) TF_ROUND(6u)
  x0 += k0;  x1 += k1 + 3u;
  TF_ROUND(17u) TF_ROUND(29u) TF_ROUND(16u) TF_ROUND(24u)
  x0 += k1;  x1 += ks2 + 4u;
  TF_ROUND(13u) TF_ROUND(15u) TF_ROUND(26u) TF_ROUND(6u)
  x0 += ks2; x1 += k0 + 5u;
#undef TF_ROUND
  o0 = x0; o1 = x1;
}

// JAX gumbel: -log(-log(uniform(tiny,1))), logs f64-computed f32-rounded.
__device__ __forceinline__ float gumbel_f32(uint32_t bits) {
  float f = __uint_as_float((bits >> 9) | 0x3f800000u) - 1.0f;
  float u = fmaxf(1.17549435e-38f, f + 1.17549435e-38f);
  float w = (float)log((double)u);
  float t = -w;
  float g = -(float)log((double)t);
  return g;
}

// Direct global->LDS DMA, 16B per lane. LDS dest = uniform base + lane*16.
__device__ __forceinline__ void load_lds16(const float4* gsrc, void* ldst) {
  __builtin_amdgcn_global_load_lds(
      (const __attribute__((address_space(1))) void*)gsrc,
      (__attribute__((address_space(3))) void*)ldst, 16, 0, 0);
}

__global__ __launch_bounds__(NTHREADS, 1)
void gibbs_sweep(const float* __restrict__ X, const int* __restrict__ order,
                 const float* __restrict__ h, const float* __restrict__ J,
                 const float* __restrict__ betaPtr, float* __restrict__ out) {
  __shared__ __align__(16) char jbuf[NWAVES * WAVEB];  // 119680 B, wave-private
  __shared__ uint32_t sbst[(LRES / 4) * SPB];          // packed states (8 KB)
  __shared__ float    vals[QST][SPB];
  __shared__ uint32_t tk0[LRES], tk1[LRES];            // per-step threefry keys
  __shared__ int      sord[LRES];

  const int nl   = threadIdx.x;      // 0..31 local sequence
  const int a    = threadIdx.y;      // 0..20 category
  const int tid  = nl + SPB * a;     // 0..671
  const int lane = tid & 63;
  const int wv   = tid >> 6;         // wave id 0..10
  const int n0   = blockIdx.x * SPB;
  const int n    = n0 + nl;
  const float beta = betaPtr[0];

  // ---- init: keys, order cache ----
  for (int t = tid; t < LRES; t += NTHREADS) {
    uint32_t o0, o1;
    threefry2x32(0u, 42u, 0u, (uint32_t)t, o0, o1);
    tk0[t] = o0; tk1[t] = o1;
    sord[t] = order[t];
  }

  // ---- init packed state from one-hot X ----
  for (int idx = tid; idx < (LRES / 4) * SPB; idx += NTHREADS) {
    int s  = idx & (SPB - 1);
    int wg = idx / SPB;
    uint32_t w = 0;
#pragma unroll
    for (int j = 0; j < 4; ++j) {
      int l = 4 * wg + j;
      const float* xp = X + ((size_t)(n0 + s) * LRES + l) * QST;
      int b = 0;
#pragma unroll
      for (int q = 0; q < QST; ++q) b = (xp[q] > 0.5f) ? q : b;
      w |= ((uint32_t)b) << (8 * j);
    }
    sbst[wg * SPB + s] = w;
  }
  __syncthreads();

  // ---- staging (wave-private buffers; no barriers, no VGPR round-trip) ----
  const float4* Jv = (const float4*)J;
  char* wbase = jbuf + wv * WAVEB;
  const int nact = (wv == NWAVES - 1) ? 32 : 64;   // active lanes this wave
  const int nseg = (wv == NWAVES - 1) ? 1 : 2;     // a-strips this wave stages

  // 6 global_load_lds per chunk per wave (2 segs x 3 issues, or 1 seg x 6).
  auto stage = [&](int row, int c, int bsel) {
    const size_t rbu = (size_t)row * ROWU + (size_t)(c * CHU);
    for (int s = 0; s < nseg; ++s) {
      const float4* gs = Jv + rbu + (size_t)((2 * wv + s) * SEGU);
      char* lb = wbase + bsel * BUFB + s * (SEGB + SEGPAD);
      for (int k = 0; k * nact < CHU; ++k) {
        int u = k * nact + lane;
        if (u < CHU) load_lds16(gs + u, lb + k * nact * 16);
      }
    }
  };

  // per-thread LDS gather bases (buffer 0 / buffer 1, own a-strip)
  const float* gb0 = (const float*)(wbase + (a & 1) * (SEGB + SEGPAD));
  const float* gb1 = (const float*)(wbase + BUFB + (a & 1) * (SEGB + SEGPAD));

  // prologue: stage chunk 0 of step 0 into buffer 0
  stage(sord[0], 0, 0);

  // ---- sequential Gibbs sweep ----
  for (int t = 0; t < LRES; ++t) {
    const int i = sord[t];

    float tot = 0.0f, part = 0.0f;
#pragma unroll
    for (int c = 0; c < NCH; ++c) {
      if (c < NCH - 1) stage(i, c + 1, (c + 1) & 1);      // next chunk
      else stage(sord[(t + 1) & (LRES - 1)], 0, 0);       // next step's chunk 0
      // wait for current chunk's 6 loads (newest 6 = just-issued prefetch)
      asm volatile("s_waitcnt vmcnt(6)" ::: "memory");
      __builtin_amdgcn_sched_barrier(0);

      const float* gb = (c & 1) ? gb1 : gb0;
#pragma unroll
      for (int lg = 0; lg < CH / 4; ++lg) {
        uint32_t w = sbst[(c * (CH / 4) + lg) * SPB + nl];
#pragma unroll
        for (int j = 0; j < 4; ++j) {
          const int l = c * CH + 4 * lg + j;   // compile-time after unroll
          uint32_t b = (w >> (8 * j)) & 0xffu;
          float jv = gb[(4 * lg + j) * QST + b];          // LDS gather
          const int thr = KC_TBL.thr[l];                  // folds at compile time
          if (thr == 255) {
            part += jv;
          } else if (thr == 0) {
            tot += part; part = jv;
          } else {
            if ((int)b >= thr) { tot += part; part = jv; }
            else               { part += jv; tot += part; part = 0.0f; }
          }
        }
      }
    }
    tot += part;

    float lo = h[i * QST + a] + tot;

    uint32_t o0, o1;
    threefry2x32(tk0[t], tk1[t], 0u, (uint32_t)(n * QST + a), o0, o1);
    float g = gumbel_f32(o0 ^ o1);

    vals[a][nl] = g + beta * lo;
    // raw barrier with LDS-only drain: keeps prefetch loads in flight
    asm volatile("s_waitcnt lgkmcnt(0)" ::: "memory");
    __builtin_amdgcn_s_barrier();
    __builtin_amdgcn_sched_barrier(0);

    if (a == 0) {                               // first-max argmax over 21
      float best = vals[0][nl];
      int bi = 0;
#pragma unroll
      for (int q = 1; q < QST; ++q) {
        float vv = vals[q][nl];
        if (vv > best) { best = vv; bi = q; }
      }
      unsigned char* bp = reinterpret_cast<unsigned char*>(sbst);
      bp[((i >> 2) * SPB + nl) * 4 + (i & 3)] = (unsigned char)bi;
    }
    asm volatile("s_waitcnt lgkmcnt(0)" ::: "memory");
    __builtin_amdgcn_s_barrier();
    __builtin_amdgcn_sched_barrier(0);
  }

  // drain outstanding DMA before teardown/output
  asm volatile("s_waitcnt vmcnt(0)" ::: "memory");

  // ---- expand packed state to one-hot f32 output ----
  const size_t base = (size_t)n0 * LRES * QST;
  for (int idx = tid; idx < SPB * LRES * QST; idx += NTHREADS) {
    int s   = idx / (LRES * QST);
    int rem = idx - s * (LRES * QST);
    int l   = rem / QST;
    int q   = rem - l * QST;
    uint32_t w = sbst[(l >> 2) * SPB + s];
    int b = (int)((w >> (8 * (l & 3))) & 0xffu);
    out[base + idx] = (b == q) ? 1.0f : 0.0f;
  }
}

extern "C" void kernel_launch(void* const* d_in, const int* in_sizes, int n_in,
                              void* d_out, int out_size, void* d_ws, size_t ws_size,
                              hipStream_t stream) {
  const float* X     = (const float*)d_in[0];
  const int*   order = (const int*)  d_in[1];
  const float* h     = (const float*)d_in[2];
  const float* J     = (const float*)d_in[3];
  const float* beta  = (const float*)d_in[4];
  float* out = (float*)d_out;

  dim3 grid(NSEQ / SPB);      // 256 blocks, 1 per CU
  dim3 block(SPB, QST);       // 32 x 21 = 672 threads
  hipLaunchKernelGGL(gibbs_sweep, grid, block, 0, stream, X, order, h, J, beta, out);
}